// Round 9
// baseline (493.825 us; speedup 1.0000x reference)
//
#include <hip/hip_runtime.h>
#include <hip/hip_bf16.h>

typedef __attribute__((ext_vector_type(4))) float  f32x4;
typedef __attribute__((ext_vector_type(8))) short  bf16x8;
typedef __attribute__((ext_vector_type(4))) short  short4_t;
typedef unsigned short u16;

#define SCALE_Q 0.17677669529663687f   // 32^-0.5

// native RNE float->bf16 (compiler packs pairs into v_cvt_pk_bf16_f32)
__device__ __forceinline__ short bfc(float f) {
    __bf16 b = (__bf16)f;
    union { __bf16 b; short s; } u; u.b = b; return u.s;
}

__device__ __forceinline__ bf16x8 pack8(f32x4 a, f32x4 b) {
    bf16x8 o;
    o[0] = bfc(a[0]); o[1] = bfc(a[1]); o[2] = bfc(a[2]); o[3] = bfc(a[3]);
    o[4] = bfc(b[0]); o[5] = bfc(b[1]); o[6] = bfc(b[2]); o[7] = bfc(b[3]);
    return o;
}

__device__ __forceinline__ void load_lds16(const void* g, void* l) {
    __builtin_amdgcn_global_load_lds(
        (const __attribute__((address_space(1))) void*)g,
        (__attribute__((address_space(3))) void*)l, 16, 0, 0);
}

// ---------------------------------------------------------------------------
// All four 512x512 weights fp32->bf16 in one launch.
// ---------------------------------------------------------------------------
__global__ __launch_bounds__(256) void wcvt_kernel(
        const float* __restrict__ w0, const float* __restrict__ w1,
        const float* __restrict__ w2, const float* __restrict__ w3,
        u16* __restrict__ d0, u16* __restrict__ d1,
        u16* __restrict__ d2, u16* __restrict__ d3)
{
    const float* s = (blockIdx.y == 0) ? w0 : (blockIdx.y == 1) ? w1
                   : (blockIdx.y == 2) ? w2 : w3;
    u16* d = (blockIdx.y == 0) ? d0 : (blockIdx.y == 1) ? d1
           : (blockIdx.y == 2) ? d2 : d3;
    const int i = blockIdx.x * 256 + threadIdx.x;   // 32768 per matrix
    const float4* sp = (const float4*)s + (size_t)i * 2;
    const float4 a = sp[0], b = sp[1];
    bf16x8 o;
    o[0] = bfc(a.x); o[1] = bfc(a.y); o[2] = bfc(a.z); o[3] = bfc(a.w);
    o[4] = bfc(b.x); o[5] = bfc(b.y); o[6] = bfc(b.z); o[7] = bfc(b.w);
    *((bf16x8*)d + i) = o;
}

// ---------------------------------------------------------------------------
// cwb[w][h][i][j] = bias_table[REL_IDX[i][j]][h] + mask[w][i][j]   (fp32)
// ---------------------------------------------------------------------------
__global__ __launch_bounds__(256) void cwb_kernel(
        const float* __restrict__ bias_table,   // [225][16]
        const float* __restrict__ mask,         // [64][64][64]
        float* __restrict__ cwb)                // [64][16][64][64]
{
    const int wh = blockIdx.x;          // w*16 + h
    const int w = wh >> 4, h = wh & 15;
    for (int e = threadIdx.x; e < 4096; e += 256) {
        const int i = e >> 6, j = e & 63;
        const int rel = ((i >> 3) - (j >> 3) + 7) * 15 + (i & 7) - (j & 7) + 7;
        cwb[(size_t)wh * 4096 + e] = bias_table[rel * 16 + h] + mask[(size_t)w * 4096 + e];
    }
}

// ---------------------------------------------------------------------------
// QKV projection GEMM, fp32-A direct, DOUBLE-BUFFERED with counted vmcnt.
// C[65536,512] = A_f32 @ W_b16^T + bias (*scale for q).
// 128x128 tile, BK=32, 4 waves (2x2), 16x16x32 bf16 MFMA.
// LDS: 2 x (A 16KB + B 8KB) = 48KB -> 3 blocks/CU.
// Schedule/K-tile: STAGE(kt+1) -> vmcnt(6) -> s_barrier -> COMPUTE(kt) -> s_barrier.
// vmcnt(6) leaves the 6 just-issued loads in flight across the whole compute.
// Swizzles (write pre-swizzles GLOBAL src col, read applies same XOR):
//   A fp32 (128B rows, 8 slots): slot = blk ^ (row&7)
//   B bf16 ( 64B rows, 4 slots): slot = blk ^ ((row>>1)&3)   [bank-complete]
// blockIdx.y selects q/k/v; y<2 -> out [b][h][t][d], y==2 -> vt [b][h][d][t].
// ---------------------------------------------------------------------------
__global__ __launch_bounds__(256) void gemm_qkv(
        const float* __restrict__ q, const float* __restrict__ k,
        const float* __restrict__ v,
        const u16* __restrict__ wq, const u16* __restrict__ wk,
        const u16* __restrict__ wv,
        const float* __restrict__ bq, const float* __restrict__ bk,
        const float* __restrict__ bv,
        u16* __restrict__ qh, u16* __restrict__ kh, u16* __restrict__ vt)
{
    __shared__ __align__(16) float Asf[2][4096];   // 2 x 16 KB
    __shared__ __align__(16) u16   Bs[2][4096];    // 2 x  8 KB

    const int which = blockIdx.y;
    const float* A    = (which == 0) ? q  : (which == 1) ? k  : v;
    const u16*   Wb   = (which == 0) ? wq : (which == 1) ? wk : wv;
    const float* bias = (which == 0) ? bq : (which == 1) ? bk : bv;
    const float scale = (which == 0) ? SCALE_Q : 1.0f;
    u16* outp         = (which == 0) ? qh : (which == 1) ? kh : vt;

    // XCD swizzle: 2048 x-wgs, 8 XCDs, 256 contiguous per XCD
    const int wg = (blockIdx.x & 7) * 256 + (blockIdx.x >> 3);
    const int m0 = (wg >> 2) << 7;
    const int n0 = (wg & 3) << 7;

    const int t = threadIdx.x;
    const int lane = t & 63, wv_ = t >> 6;
    const int g = lane >> 4, ln = lane & 15;
    const int wr = wv_ >> 1, wc = wv_ & 1;

    const float* Ab = A  + (size_t)m0 * 512;
    const u16*   Bb = Wb + (size_t)n0 * 512;

    f32x4 acc[4][4];
#pragma unroll
    for (int i = 0; i < 4; i++)
#pragma unroll
        for (int j = 0; j < 4; j++) acc[i][j] = {0.f, 0.f, 0.f, 0.f};

#define STAGEQ(KT, BUF) do {                                                 \
    _Pragma("unroll")                                                        \
    for (int c = 0; c < 4; c++) {                                            \
        const int bi = (c << 8) + t, row = bi >> 3, blk = bi & 7;            \
        const int col = ((KT) << 5) + ((blk ^ (row & 7)) << 2);              \
        load_lds16(Ab + (size_t)row * 512 + col, &Asf[BUF][bi << 2]);        \
    }                                                                        \
    _Pragma("unroll")                                                        \
    for (int c = 0; c < 2; c++) {                                            \
        const int bi = (c << 8) + t, row = bi >> 2, blk = bi & 3;            \
        const int col = ((KT) << 5) + ((blk ^ ((row >> 1) & 3)) << 3);       \
        load_lds16(Bb + (size_t)row * 512 + col, &Bs[BUF][bi << 3]);         \
    }                                                                        \
} while (0)

#define COMPQ(BUF) do {                                                      \
    bf16x8 af[4], bfr[4];                                                    \
    _Pragma("unroll")                                                        \
    for (int mt = 0; mt < 4; mt++) {                                         \
        const int rm = (wr << 6) + (mt << 4) + ln;                           \
        const int p0 = ((g << 1)    ) ^ (rm & 7);                            \
        const int p1 = ((g << 1) + 1) ^ (rm & 7);                            \
        const f32x4 lo = *(const f32x4*)&Asf[BUF][(rm << 5) + (p0 << 2)];    \
        const f32x4 hi = *(const f32x4*)&Asf[BUF][(rm << 5) + (p1 << 2)];    \
        af[mt] = pack8(lo, hi);                                              \
    }                                                                        \
    _Pragma("unroll")                                                        \
    for (int nt = 0; nt < 4; nt++) {                                         \
        const int rn = (wc << 6) + (nt << 4) + ln;                           \
        const int sl = g ^ ((rn >> 1) & 3);                                  \
        bfr[nt] = *(const bf16x8*)&Bs[BUF][(rn << 5) + (sl << 3)];           \
    }                                                                        \
    _Pragma("unroll")                                                        \
    for (int mt = 0; mt < 4; mt++)                                           \
        _Pragma("unroll")                                                    \
        for (int nt = 0; nt < 4; nt++)                                       \
            acc[mt][nt] = __builtin_amdgcn_mfma_f32_16x16x32_bf16(           \
                af[mt], bfr[nt], acc[mt][nt], 0, 0, 0);                      \
} while (0)

    STAGEQ(0, 0);
    for (int kt = 0; kt < 16; ++kt) {
        if (kt < 15) {
            if ((kt & 1) == 0) STAGEQ(kt + 1, 1); else STAGEQ(kt + 1, 0);
            asm volatile("s_waitcnt vmcnt(6)" ::: "memory");
        } else {
            asm volatile("s_waitcnt vmcnt(0)" ::: "memory");
        }
        __builtin_amdgcn_s_barrier();
        asm volatile("" ::: "memory");
        if ((kt & 1) == 0) COMPQ(0); else COMPQ(1);
        asm volatile("" ::: "memory");
        __builtin_amdgcn_s_barrier();
        asm volatile("" ::: "memory");
    }
#undef STAGEQ
#undef COMPQ

    // ---- epilogue: bias, scale, store ----
#pragma unroll
    for (int mt = 0; mt < 4; mt++) {
#pragma unroll
        for (int nt = 0; nt < 4; nt++) {
            const int n = n0 + (wc << 6) + (nt << 4) + ln;
            const float bv_ = bias[n];
            const int mbase = m0 + (wr << 6) + (mt << 4) + (g << 2);
            if (which < 2) {
#pragma unroll
                for (int r = 0; r < 4; r++) {
                    const int m = mbase + r;
                    const int b = m >> 6, tt = m & 63, hh = n >> 5, d = n & 31;
                    outp[((size_t)(b * 16 + hh) * 64 + tt) * 32 + d] =
                        (u16)bfc((acc[mt][nt][r] + bv_) * scale);
                }
            } else {
                short4_t hq;
#pragma unroll
                for (int r = 0; r < 4; r++) hq[r] = bfc(acc[mt][nt][r] + bv_);
                const int b = mbase >> 6, tt = mbase & 63, hh = n >> 5, d = n & 31;
                *(short4_t*)&outp[((size_t)(b * 16 + hh) * 32 + d) * 64 + tt] = hq;
            }
        }
    }
}

// ---------------------------------------------------------------------------
// Final projection (bf16 A), same dbuf/counted-vmcnt structure, BK=32.
// LDS: 2 x (8KB + 8KB) = 32KB -> 5 blocks/CU. out fp32 [m][n].
// bf16 64B rows -> slot = blk ^ ((row>>1)&3) on both A and B.
// ---------------------------------------------------------------------------
__global__ __launch_bounds__(256) void gemm_out(
        const u16* __restrict__ A, const u16* __restrict__ Wb,
        const float* __restrict__ bias, float* __restrict__ outp)
{
    __shared__ __align__(16) u16 As[2][4096];
    __shared__ __align__(16) u16 Bs[2][4096];

    const int wg = (blockIdx.x & 7) * 256 + (blockIdx.x >> 3);
    const int m0 = (wg >> 2) << 7;
    const int n0 = (wg & 3) << 7;

    const int t = threadIdx.x;
    const int lane = t & 63, wv_ = t >> 6;
    const int g = lane >> 4, ln = lane & 15;
    const int wr = wv_ >> 1, wc = wv_ & 1;

    const u16* Ab = A  + (size_t)m0 * 512;
    const u16* Bb = Wb + (size_t)n0 * 512;

    f32x4 acc[4][4];
#pragma unroll
    for (int i = 0; i < 4; i++)
#pragma unroll
        for (int j = 0; j < 4; j++) acc[i][j] = {0.f, 0.f, 0.f, 0.f};

#define STAGEO(KT, BUF) do {                                                 \
    _Pragma("unroll")                                                        \
    for (int c = 0; c < 2; c++) {                                            \
        const int bi = (c << 8) + t, row = bi >> 2, blk = bi & 3;            \
        const int col = ((KT) << 5) + ((blk ^ ((row >> 1) & 3)) << 3);       \
        load_lds16(Ab + (size_t)row * 512 + col, &As[BUF][bi << 3]);         \
        load_lds16(Bb + (size_t)row * 512 + col, &Bs[BUF][bi << 3]);         \
    }                                                                        \
} while (0)

#define COMPO(BUF) do {                                                      \
    bf16x8 af[4], bfr[4];                                                    \
    _Pragma("unroll")                                                        \
    for (int mt = 0; mt < 4; mt++) {                                         \
        const int rm = (wr << 6) + (mt << 4) + ln;                           \
        const int sl = g ^ ((rm >> 1) & 3);                                  \
        af[mt] = *(const bf16x8*)&As[BUF][(rm << 5) + (sl << 3)];            \
    }                                                                        \
    _Pragma("unroll")                                                        \
    for (int nt = 0; nt < 4; nt++) {                                         \
        const int rn = (wc << 6) + (nt << 4) + ln;                           \
        const int sl = g ^ ((rn >> 1) & 3);                                  \
        bfr[nt] = *(const bf16x8*)&Bs[BUF][(rn << 5) + (sl << 3)];           \
    }                                                                        \
    _Pragma("unroll")                                                        \
    for (int mt = 0; mt < 4; mt++)                                           \
        _Pragma("unroll")                                                    \
        for (int nt = 0; nt < 4; nt++)                                       \
            acc[mt][nt] = __builtin_amdgcn_mfma_f32_16x16x32_bf16(           \
                af[mt], bfr[nt], acc[mt][nt], 0, 0, 0);                      \
} while (0)

    STAGEO(0, 0);
    for (int kt = 0; kt < 16; ++kt) {
        if (kt < 15) {
            if ((kt & 1) == 0) STAGEO(kt + 1, 1); else STAGEO(kt + 1, 0);
            asm volatile("s_waitcnt vmcnt(4)" ::: "memory");
        } else {
            asm volatile("s_waitcnt vmcnt(0)" ::: "memory");
        }
        __builtin_amdgcn_s_barrier();
        asm volatile("" ::: "memory");
        if ((kt & 1) == 0) COMPO(0); else COMPO(1);
        asm volatile("" ::: "memory");
        __builtin_amdgcn_s_barrier();
        asm volatile("" ::: "memory");
    }
#undef STAGEO
#undef COMPO

#pragma unroll
    for (int mt = 0; mt < 4; mt++) {
#pragma unroll
        for (int nt = 0; nt < 4; nt++) {
            const int n = n0 + (wc << 6) + (nt << 4) + ln;
            const float bv_ = bias[n];
            const int mbase = m0 + (wr << 6) + (mt << 4) + (g << 2);
#pragma unroll
            for (int r = 0; r < 4; r++) {
                const int m = mbase + r;
                outp[(size_t)m * 512 + n] = acc[mt][nt][r] + bv_;
            }
        }
    }
}

// ---------------------------------------------------------------------------
// Attention: 4 waves/block, one (b,h) per wave. S^T = K·Q^T via mfma(K,Q);
// softmax over j = local reduce + shfl_xor 16/32; P -> private LDS region
// bf16 [i][j] XOR-swizzled; O^T = V^T·P.
// qh,kh: [b][h][t][d] bf16 ; vt: [b][h][d][t] bf16 ; x out: [b][t][h*32+d] bf16
// ---------------------------------------------------------------------------
__global__ __launch_bounds__(256) void attn_kernel(
        const u16* __restrict__ qh, const u16* __restrict__ kh,
        const u16* __restrict__ vt, const float* __restrict__ cwb,
        u16* __restrict__ xout)
{
    __shared__ __align__(16) u16 P[16384];   // 4 waves x 8 KB

    const int wv_ = threadIdx.x >> 6;
    const int bid = (blockIdx.x << 2) + wv_;    // b*16 + h
    const int b = bid >> 4, h = bid & 15, w = b & 63;
    const int lane = threadIdx.x & 63, g = lane >> 4, ln = lane & 15;
    const size_t base = (size_t)bid * 2048;
    u16* Pw = &P[wv_ << 12];

    bf16x8 kf[4], qf[4];
#pragma unroll
    for (int mt = 0; mt < 4; mt++)
        kf[mt] = *(const bf16x8*)&kh[base + (mt * 16 + ln) * 32 + g * 8];
#pragma unroll
    for (int nt = 0; nt < 4; nt++)
        qf[nt] = *(const bf16x8*)&qh[base + (nt * 16 + ln) * 32 + g * 8];

    f32x4 acc[4][4];   // acc[mt][nt]: rows j = mt*16+g*4+r, cols i = nt*16+ln
#pragma unroll
    for (int i = 0; i < 4; i++)
#pragma unroll
        for (int j = 0; j < 4; j++) acc[i][j] = {0.f, 0.f, 0.f, 0.f};

#pragma unroll
    for (int mt = 0; mt < 4; mt++)
#pragma unroll
        for (int nt = 0; nt < 4; nt++)
            acc[mt][nt] = __builtin_amdgcn_mfma_f32_16x16x32_bf16(
                kf[mt], qf[nt], acc[mt][nt], 0, 0, 0);

    const float* cw = cwb + (size_t)(w * 16 + h) * 4096;
#pragma unroll
    for (int nt = 0; nt < 4; nt++) {
        const int i = nt * 16 + ln;
#pragma unroll
        for (int mt = 0; mt < 4; mt++) {
            const float4 bm = *(const float4*)&cw[i * 64 + mt * 16 + (g << 2)];
            acc[mt][nt][0] += bm.x; acc[mt][nt][1] += bm.y;
            acc[mt][nt][2] += bm.z; acc[mt][nt][3] += bm.w;
        }
    }

#pragma unroll
    for (int nt = 0; nt < 4; nt++) {
        float mx = acc[0][nt][0];
#pragma unroll
        for (int mt = 0; mt < 4; mt++)
#pragma unroll
            for (int r = 0; r < 4; r++) mx = fmaxf(mx, acc[mt][nt][r]);
        mx = fmaxf(mx, __shfl_xor(mx, 16));
        mx = fmaxf(mx, __shfl_xor(mx, 32));
        float sum = 0.f;
#pragma unroll
        for (int mt = 0; mt < 4; mt++)
#pragma unroll
            for (int r = 0; r < 4; r++) {
                const float p = __expf(acc[mt][nt][r] - mx);
                acc[mt][nt][r] = p;
                sum += p;
            }
        sum += __shfl_xor(sum, 16);
        sum += __shfl_xor(sum, 32);
        const float rs = 1.0f / sum;
        const int i = nt * 16 + ln;
#pragma unroll
        for (int mt = 0; mt < 4; mt++) {
            short4_t hq;
#pragma unroll
            for (int r = 0; r < 4; r++) hq[r] = bfc(acc[mt][nt][r] * rs);
            const int idx = (i * 64 + mt * 16 + (g << 2)) ^ ((i & 7) << 3);
            *(short4_t*)&Pw[idx] = hq;
        }
    }
    __syncthreads();

    f32x4 oacc[2][4];
#pragma unroll
    for (int i = 0; i < 2; i++)
#pragma unroll
        for (int j = 0; j < 4; j++) oacc[i][j] = {0.f, 0.f, 0.f, 0.f};

#pragma unroll
    for (int ks = 0; ks < 2; ks++) {
        bf16x8 vf[2], pf[4];
#pragma unroll
        for (int mt = 0; mt < 2; mt++)
            vf[mt] = *(const bf16x8*)&vt[base + (mt * 16 + ln) * 64 + ks * 32 + g * 8];
#pragma unroll
        for (int nt = 0; nt < 4; nt++) {
            const int i = nt * 16 + ln;
            pf[nt] = *(const bf16x8*)&Pw[(i * 64 + ks * 32 + g * 8) ^ ((i & 7) << 3)];
        }
#pragma unroll
        for (int mt = 0; mt < 2; mt++)
#pragma unroll
            for (int nt = 0; nt < 4; nt++)
                oacc[mt][nt] = __builtin_amdgcn_mfma_f32_16x16x32_bf16(
                    vf[mt], pf[nt], oacc[mt][nt], 0, 0, 0);
    }

#pragma unroll
    for (int mt = 0; mt < 2; mt++) {
#pragma unroll
        for (int nt = 0; nt < 4; nt++) {
            const int i = nt * 16 + ln, d0 = mt * 16 + (g << 2);
            short4_t hq;
#pragma unroll
            for (int r = 0; r < 4; r++) hq[r] = bfc(oacc[mt][nt][r]);
            *(short4_t*)&xout[((size_t)b * 64 + i) * 512 + h * 32 + d0] = hq;
        }
    }
}

// ---------------------------------------------------------------------------
extern "C" void kernel_launch(void* const* d_in, const int* in_sizes, int n_in,
                              void* d_out, int out_size, void* d_ws, size_t ws_size,
                              hipStream_t stream) {
    const float* q    = (const float*)d_in[0];
    const float* k    = (const float*)d_in[1];
    const float* v    = (const float*)d_in[2];
    const float* mask = (const float*)d_in[3];
    const float* Wq   = (const float*)d_in[4];
    const float* bq   = (const float*)d_in[5];
    const float* Wk   = (const float*)d_in[6];
    const float* bk   = (const float*)d_in[7];
    const float* Wv   = (const float*)d_in[8];
    const float* bv   = (const float*)d_in[9];
    const float* Wp   = (const float*)d_in[10];
    const float* bp   = (const float*)d_in[11];
    const float* bias_table = (const float*)d_in[12];
    float* out = (float*)d_out;

    // ws layout (bytes): t0 (attn out bf16) | qh | kh | vt | cwb | 4x W bf16
    char* ws = (char*)d_ws;
    u16*   t0  = (u16*)(ws);
    u16*   qh  = (u16*)(ws + 67108864);
    u16*   kh  = (u16*)(ws + 134217728);
    u16*   vt  = (u16*)(ws + 201326592);
    float* cwb = (float*)(ws + 268435456);
    u16*   wqb = (u16*)(ws + 285212672);
    u16*   wkb = (u16*)(ws + 285736960);
    u16*   wvb = (u16*)(ws + 286261248);
    u16*   wpb = (u16*)(ws + 286785536);

    cwb_kernel<<<1024, 256, 0, stream>>>(bias_table, mask, cwb);
    wcvt_kernel<<<dim3(128, 4), 256, 0, stream>>>(Wq, Wk, Wv, Wp, wqb, wkb, wvb, wpb);

    gemm_qkv<<<dim3(2048, 3), 256, 0, stream>>>(q, k, v, wqb, wkb, wvb,
                                                bq, bk, bv, qh, kh, vt);

    attn_kernel<<<4096, 256, 0, stream>>>(qh, kh, vt, cwb, t0);

    gemm_out<<<2048, 256, 0, stream>>>(t0, wpb, bp, out);
}

// Round 13
// 429.102 us; speedup vs baseline: 1.1508x; 1.1508x over previous
//
#include <hip/hip_runtime.h>
#include <hip/hip_bf16.h>

typedef __attribute__((ext_vector_type(4))) float  f32x4;
typedef __attribute__((ext_vector_type(8))) short  bf16x8;
typedef __attribute__((ext_vector_type(4))) short  short4_t;
typedef unsigned short u16;

#define SCALE_Q 0.17677669529663687f   // 32^-0.5

// native RNE float->bf16 (compiler packs pairs into v_cvt_pk_bf16_f32)
__device__ __forceinline__ short bfc(float f) {
    __bf16 b = (__bf16)f;
    union { __bf16 b; short s; } u; u.b = b; return u.s;
}

__device__ __forceinline__ void load_lds16(const void* g, void* l) {
    __builtin_amdgcn_global_load_lds(
        (const __attribute__((address_space(1))) void*)g,
        (__attribute__((address_space(3))) void*)l, 16, 0, 0);
}

// ---------------------------------------------------------------------------
// fp32 -> bf16 convert (activations), 8 elems/thread. Proven ~36 us (r2).
// ---------------------------------------------------------------------------
__global__ __launch_bounds__(256) void cvt_kernel(
        const float* __restrict__ s, u16* __restrict__ d, int n8)
{
    const int i = blockIdx.x * 256 + threadIdx.x;
    if (i >= n8) return;
    const float4* sp = (const float4*)s + (size_t)i * 2;
    const float4 a = sp[0], b = sp[1];
    bf16x8 o;
    o[0] = bfc(a.x); o[1] = bfc(a.y); o[2] = bfc(a.z); o[3] = bfc(a.w);
    o[4] = bfc(b.x); o[5] = bfc(b.y); o[6] = bfc(b.z); o[7] = bfc(b.w);
    *((bf16x8*)d + i) = o;
}

// All four 512x512 weights in one launch.
__global__ __launch_bounds__(256) void wcvt_kernel(
        const float* __restrict__ w0, const float* __restrict__ w1,
        const float* __restrict__ w2, const float* __restrict__ w3,
        u16* __restrict__ d0, u16* __restrict__ d1,
        u16* __restrict__ d2, u16* __restrict__ d3)
{
    const float* s = (blockIdx.y == 0) ? w0 : (blockIdx.y == 1) ? w1
                   : (blockIdx.y == 2) ? w2 : w3;
    u16* d = (blockIdx.y == 0) ? d0 : (blockIdx.y == 1) ? d1
           : (blockIdx.y == 2) ? d2 : d3;
    const int i = blockIdx.x * 256 + threadIdx.x;   // 32768 per matrix
    const float4* sp = (const float4*)s + (size_t)i * 2;
    const float4 a = sp[0], b = sp[1];
    bf16x8 o;
    o[0] = bfc(a.x); o[1] = bfc(a.y); o[2] = bfc(a.z); o[3] = bfc(a.w);
    o[4] = bfc(b.x); o[5] = bfc(b.y); o[6] = bfc(b.z); o[7] = bfc(b.w);
    *((bf16x8*)d + i) = o;
}

// ---------------------------------------------------------------------------
// cwb[w][h][i][j] = bias_table[REL_IDX[i][j]][h] + mask[w][i][j]   (fp32)
// ---------------------------------------------------------------------------
__global__ __launch_bounds__(256) void cwb_kernel(
        const float* __restrict__ bias_table,   // [225][16]
        const float* __restrict__ mask,         // [64][64][64]
        float* __restrict__ cwb)                // [64][16][64][64]
{
    const int wh = blockIdx.x;          // w*16 + h
    const int w = wh >> 4, h = wh & 15;
    for (int e = threadIdx.x; e < 4096; e += 256) {
        const int i = e >> 6, j = e & 63;
        const int rel = ((i >> 3) - (j >> 3) + 7) * 15 + (i & 7) - (j & 7) + 7;
        cwb[(size_t)wh * 4096 + e] = bias_table[rel * 16 + h] + mask[(size_t)w * 4096 + e];
    }
}

// ---------------------------------------------------------------------------
// bf16 GEMM, m97 structure (proven ~60 us/instance): 128x128 tile, BK=64,
// 4 waves (2x2), single-buffer 2-barrier loop, global_load_lds 16B with
// pre-swizzled GLOBAL source (slot = blk ^ (row&7), 8 slots per 128B row),
// XCD-aware block swizzle (2048 wgs, 256/XCD).
// C[65536,512] = A_b16 @ W_b16^T + bias, * scale.
// OMODE: 0 = bf16 out [b][h][t][d]; 1 = bf16 out [b][h][d][t]; 2 = fp32 [m][n]
// ---------------------------------------------------------------------------
template<int OMODE>
__global__ __launch_bounds__(256) void gemm_b(
        const u16* __restrict__ A, const u16* __restrict__ Wb,
        const float* __restrict__ bias, float scale, void* __restrict__ outp)
{
    __shared__ __align__(16) u16 As[8192];   // [128][64] swizzled
    __shared__ __align__(16) u16 Bs[8192];

    const int wg = (blockIdx.x & 7) * 256 + (blockIdx.x >> 3);
    const int m0 = (wg >> 2) << 7;
    const int n0 = (wg & 3) << 7;

    const int t = threadIdx.x;
    const int lane = t & 63, wv = t >> 6;
    const int g = lane >> 4, ln = lane & 15;
    const int wr = wv >> 1, wc = wv & 1;
    const int wbase = wv << 6;

    f32x4 acc[4][4];
#pragma unroll
    for (int i = 0; i < 4; i++)
#pragma unroll
        for (int j = 0; j < 4; j++) acc[i][j] = {0.f, 0.f, 0.f, 0.f};

    const u16* Abase = A  + (size_t)m0 * 512;
    const u16* Bbase = Wb + (size_t)n0 * 512;

    for (int k0 = 0; k0 < 512; k0 += 64) {
#pragma unroll
        for (int c = 0; c < 4; c++) {
            const int bi  = (c << 8) + wbase + lane;      // 16B-block 0..1023
            const int row = bi >> 3;
            const int cbs = (bi & 7) ^ (row & 7);
            const size_t go = (size_t)row * 512 + k0 + (cbs << 3);
            load_lds16(Abase + go, &As[((c << 8) + wbase) << 3]);
            load_lds16(Bbase + go, &Bs[((c << 8) + wbase) << 3]);
        }
        __syncthreads();
#pragma unroll
        for (int ks = 0; ks < 2; ks++) {
            bf16x8 af[4], bfr[4];
#pragma unroll
            for (int mt = 0; mt < 4; mt++) {
                const int row = (wr << 6) + (mt << 4) + ln;
                af[mt] = *(const bf16x8*)&As[(row << 6) + ((((ks << 2) + g) ^ (row & 7)) << 3)];
            }
#pragma unroll
            for (int nt = 0; nt < 4; nt++) {
                const int row = (wc << 6) + (nt << 4) + ln;
                bfr[nt] = *(const bf16x8*)&Bs[(row << 6) + ((((ks << 2) + g) ^ (row & 7)) << 3)];
            }
#pragma unroll
            for (int mt = 0; mt < 4; mt++)
#pragma unroll
                for (int nt = 0; nt < 4; nt++)
                    acc[mt][nt] = __builtin_amdgcn_mfma_f32_16x16x32_bf16(
                        af[mt], bfr[nt], acc[mt][nt], 0, 0, 0);
        }
        __syncthreads();
    }

    // ---- epilogue: bias, scale, store ----
#pragma unroll
    for (int mt = 0; mt < 4; mt++) {
#pragma unroll
        for (int nt = 0; nt < 4; nt++) {
            const int n = n0 + (wc << 6) + (nt << 4) + ln;
            const float bv = bias[n];
            const int mbase = m0 + (wr << 6) + (mt << 4) + (g << 2);
            if (OMODE == 0) {
#pragma unroll
                for (int r = 0; r < 4; r++) {
                    const int m = mbase + r;
                    const int b = m >> 6, tt = m & 63, hh = n >> 5, d = n & 31;
                    ((u16*)outp)[((size_t)(b * 16 + hh) * 64 + tt) * 32 + d] =
                        (u16)bfc((acc[mt][nt][r] + bv) * scale);
                }
            } else if (OMODE == 1) {
                short4_t hq;
#pragma unroll
                for (int r = 0; r < 4; r++) hq[r] = bfc((acc[mt][nt][r] + bv) * scale);
                const int b = mbase >> 6, tt = mbase & 63, hh = n >> 5, d = n & 31;
                *(short4_t*)&((u16*)outp)[((size_t)(b * 16 + hh) * 32 + d) * 64 + tt] = hq;
            } else {
#pragma unroll
                for (int r = 0; r < 4; r++) {
                    const int m = mbase + r;
                    ((float*)outp)[(size_t)m * 512 + n] = (acc[mt][nt][r] + bv) * scale;
                }
            }
        }
    }
}

// ---------------------------------------------------------------------------
// Attention: 4 waves/block, one (b,h) per wave (proven ~10-15 us).
// S^T = K·Q^T via mfma(K,Q); softmax over j = local reduce + shfl_xor 16/32;
// P -> private LDS region bf16 [i][j] XOR-swizzled; O^T = V^T·P.
// qh,kh: [b][h][t][d] bf16 ; vt: [b][h][d][t] bf16 ; x out: [b][t][h*32+d] bf16
// ---------------------------------------------------------------------------
__global__ __launch_bounds__(256) void attn_kernel(
        const u16* __restrict__ qh, const u16* __restrict__ kh,
        const u16* __restrict__ vt, const float* __restrict__ cwb,
        u16* __restrict__ xout)
{
    __shared__ __align__(16) u16 P[16384];   // 4 waves x 8 KB

    const int wv = threadIdx.x >> 6;
    const int bid = (blockIdx.x << 2) + wv;     // b*16 + h
    const int b = bid >> 4, h = bid & 15, w = b & 63;
    const int lane = threadIdx.x & 63, g = lane >> 4, ln = lane & 15;
    const size_t base = (size_t)bid * 2048;
    u16* Pw = &P[wv << 12];

    bf16x8 kf[4], qf[4];
#pragma unroll
    for (int mt = 0; mt < 4; mt++)
        kf[mt] = *(const bf16x8*)&kh[base + (mt * 16 + ln) * 32 + g * 8];
#pragma unroll
    for (int nt = 0; nt < 4; nt++)
        qf[nt] = *(const bf16x8*)&qh[base + (nt * 16 + ln) * 32 + g * 8];

    f32x4 acc[4][4];   // acc[mt][nt]: rows j = mt*16+g*4+r, cols i = nt*16+ln
#pragma unroll
    for (int i = 0; i < 4; i++)
#pragma unroll
        for (int j = 0; j < 4; j++) acc[i][j] = {0.f, 0.f, 0.f, 0.f};

#pragma unroll
    for (int mt = 0; mt < 4; mt++)
#pragma unroll
        for (int nt = 0; nt < 4; nt++)
            acc[mt][nt] = __builtin_amdgcn_mfma_f32_16x16x32_bf16(
                kf[mt], qf[nt], acc[mt][nt], 0, 0, 0);

    const float* cw = cwb + (size_t)(w * 16 + h) * 4096;
#pragma unroll
    for (int nt = 0; nt < 4; nt++) {
        const int i = nt * 16 + ln;
#pragma unroll
        for (int mt = 0; mt < 4; mt++) {
            const float4 bm = *(const float4*)&cw[i * 64 + mt * 16 + (g << 2)];
            acc[mt][nt][0] += bm.x; acc[mt][nt][1] += bm.y;
            acc[mt][nt][2] += bm.z; acc[mt][nt][3] += bm.w;
        }
    }

#pragma unroll
    for (int nt = 0; nt < 4; nt++) {
        float mx = acc[0][nt][0];
#pragma unroll
        for (int mt = 0; mt < 4; mt++)
#pragma unroll
            for (int r = 0; r < 4; r++) mx = fmaxf(mx, acc[mt][nt][r]);
        mx = fmaxf(mx, __shfl_xor(mx, 16));
        mx = fmaxf(mx, __shfl_xor(mx, 32));
        float sum = 0.f;
#pragma unroll
        for (int mt = 0; mt < 4; mt++)
#pragma unroll
            for (int r = 0; r < 4; r++) {
                const float p = __expf(acc[mt][nt][r] - mx);
                acc[mt][nt][r] = p;
                sum += p;
            }
        sum += __shfl_xor(sum, 16);
        sum += __shfl_xor(sum, 32);
        const float rs = 1.0f / sum;
        const int i = nt * 16 + ln;
#pragma unroll
        for (int mt = 0; mt < 4; mt++) {
            short4_t hq;
#pragma unroll
            for (int r = 0; r < 4; r++) hq[r] = bfc(acc[mt][nt][r] * rs);
            const int idx = (i * 64 + mt * 16 + (g << 2)) ^ ((i & 7) << 3);
            *(short4_t*)&Pw[idx] = hq;
        }
    }
    __syncthreads();

    f32x4 oacc[2][4];
#pragma unroll
    for (int i = 0; i < 2; i++)
#pragma unroll
        for (int j = 0; j < 4; j++) oacc[i][j] = {0.f, 0.f, 0.f, 0.f};

#pragma unroll
    for (int ks = 0; ks < 2; ks++) {
        bf16x8 vf[2], pf[4];
#pragma unroll
        for (int mt = 0; mt < 2; mt++)
            vf[mt] = *(const bf16x8*)&vt[base + (mt * 16 + ln) * 64 + ks * 32 + g * 8];
#pragma unroll
        for (int nt = 0; nt < 4; nt++) {
            const int i = nt * 16 + ln;
            pf[nt] = *(const bf16x8*)&Pw[(i * 64 + ks * 32 + g * 8) ^ ((i & 7) << 3)];
        }
#pragma unroll
        for (int mt = 0; mt < 2; mt++)
#pragma unroll
            for (int nt = 0; nt < 4; nt++)
                oacc[mt][nt] = __builtin_amdgcn_mfma_f32_16x16x32_bf16(
                    vf[mt], pf[nt], oacc[mt][nt], 0, 0, 0);
    }

#pragma unroll
    for (int mt = 0; mt < 2; mt++) {
#pragma unroll
        for (int nt = 0; nt < 4; nt++) {
            const int i = nt * 16 + ln, d0 = mt * 16 + (g << 2);
            short4_t hq;
#pragma unroll
            for (int r = 0; r < 4; r++) hq[r] = bfc(oacc[mt][nt][r]);
            *(short4_t*)&xout[((size_t)b * 64 + i) * 512 + h * 32 + d0] = hq;
        }
    }
}

// ---------------------------------------------------------------------------
extern "C" void kernel_launch(void* const* d_in, const int* in_sizes, int n_in,
                              void* d_out, int out_size, void* d_ws, size_t ws_size,
                              hipStream_t stream) {
    const float* q    = (const float*)d_in[0];
    const float* k    = (const float*)d_in[1];
    const float* v    = (const float*)d_in[2];
    const float* mask = (const float*)d_in[3];
    const float* Wq   = (const float*)d_in[4];
    const float* bq   = (const float*)d_in[5];
    const float* Wk   = (const float*)d_in[6];
    const float* bk   = (const float*)d_in[7];
    const float* Wv   = (const float*)d_in[8];
    const float* bv   = (const float*)d_in[9];
    const float* Wp   = (const float*)d_in[10];
    const float* bp   = (const float*)d_in[11];
    const float* bias_table = (const float*)d_in[12];
    float* out = (float*)d_out;

    // ws layout (bytes): t0 (act bf16 / attn out) | qh | kh | vt | cwb | 4x W
    char* ws = (char*)d_ws;
    u16*   t0  = (u16*)(ws);
    u16*   qh  = (u16*)(ws + 67108864);
    u16*   kh  = (u16*)(ws + 134217728);
    u16*   vt  = (u16*)(ws + 201326592);
    float* cwb = (float*)(ws + 268435456);
    u16*   wqb = (u16*)(ws + 285212672);
    u16*   wkb = (u16*)(ws + 285736960);
    u16*   wvb = (u16*)(ws + 286261248);
    u16*   wpb = (u16*)(ws + 286785536);

    const int n8_act = (1024 * 64 * 512) / 8;   // 4,194,304

    cwb_kernel<<<1024, 256, 0, stream>>>(bias_table, mask, cwb);
    wcvt_kernel<<<dim3(128, 4), 256, 0, stream>>>(Wq, Wk, Wv, Wp, wqb, wkb, wvb, wpb);

    cvt_kernel<<<n8_act / 256, 256, 0, stream>>>(q, t0, n8_act);
    gemm_b<0><<<2048, 256, 0, stream>>>(t0, wqb, bq, SCALE_Q, (void*)qh);

    cvt_kernel<<<n8_act / 256, 256, 0, stream>>>(k, t0, n8_act);
    gemm_b<0><<<2048, 256, 0, stream>>>(t0, wkb, bk, 1.0f, (void*)kh);

    cvt_kernel<<<n8_act / 256, 256, 0, stream>>>(v, t0, n8_act);
    gemm_b<1><<<2048, 256, 0, stream>>>(t0, wvb, bv, 1.0f, (void*)vt);

    attn_kernel<<<4096, 256, 0, stream>>>(qh, kh, vt, cwb, t0);

    gemm_b<2><<<2048, 256, 0, stream>>>(t0, wpb, bp, 1.0f, (void*)out);
}

// Round 14
// 424.490 us; speedup vs baseline: 1.1633x; 1.0109x over previous
//
#include <hip/hip_runtime.h>
#include <hip/hip_bf16.h>

typedef __attribute__((ext_vector_type(4))) float  f32x4;
typedef __attribute__((ext_vector_type(8))) short  bf16x8;
typedef __attribute__((ext_vector_type(4))) short  short4_t;
typedef unsigned short u16;

#define SCALE_Q 0.17677669529663687f   // 32^-0.5

// native RNE float->bf16 (compiler packs pairs into v_cvt_pk_bf16_f32)
__device__ __forceinline__ short bfc(float f) {
    __bf16 b = (__bf16)f;
    union { __bf16 b; short s; } u; u.b = b; return u.s;
}

__device__ __forceinline__ void load_lds16(const void* g, void* l) {
    __builtin_amdgcn_global_load_lds(
        (const __attribute__((address_space(1))) void*)g,
        (__attribute__((address_space(3))) void*)l, 16, 0, 0);
}

// ---------------------------------------------------------------------------
// fp32 -> bf16 convert (activations), 8 elems/thread. Proven ~36 us (r2).
// ---------------------------------------------------------------------------
__global__ __launch_bounds__(256) void cvt_kernel(
        const float* __restrict__ s, u16* __restrict__ d, int n8)
{
    const int i = blockIdx.x * 256 + threadIdx.x;
    if (i >= n8) return;
    const float4* sp = (const float4*)s + (size_t)i * 2;
    const float4 a = sp[0], b = sp[1];
    bf16x8 o;
    o[0] = bfc(a.x); o[1] = bfc(a.y); o[2] = bfc(a.z); o[3] = bfc(a.w);
    o[4] = bfc(b.x); o[5] = bfc(b.y); o[6] = bfc(b.z); o[7] = bfc(b.w);
    *((bf16x8*)d + i) = o;
}

// All four 512x512 weights in one launch.
__global__ __launch_bounds__(256) void wcvt_kernel(
        const float* __restrict__ w0, const float* __restrict__ w1,
        const float* __restrict__ w2, const float* __restrict__ w3,
        u16* __restrict__ d0, u16* __restrict__ d1,
        u16* __restrict__ d2, u16* __restrict__ d3)
{
    const float* s = (blockIdx.y == 0) ? w0 : (blockIdx.y == 1) ? w1
                   : (blockIdx.y == 2) ? w2 : w3;
    u16* d = (blockIdx.y == 0) ? d0 : (blockIdx.y == 1) ? d1
           : (blockIdx.y == 2) ? d2 : d3;
    const int i = blockIdx.x * 256 + threadIdx.x;   // 32768 per matrix
    const float4* sp = (const float4*)s + (size_t)i * 2;
    const float4 a = sp[0], b = sp[1];
    bf16x8 o;
    o[0] = bfc(a.x); o[1] = bfc(a.y); o[2] = bfc(a.z); o[3] = bfc(a.w);
    o[4] = bfc(b.x); o[5] = bfc(b.y); o[6] = bfc(b.z); o[7] = bfc(b.w);
    *((bf16x8*)d + i) = o;
}

// ---------------------------------------------------------------------------
// cwb[w][h][i][j] = bias_table[REL_IDX[i][j]][h] + mask[w][i][j]   (fp32)
// ---------------------------------------------------------------------------
__global__ __launch_bounds__(256) void cwb_kernel(
        const float* __restrict__ bias_table,   // [225][16]
        const float* __restrict__ mask,         // [64][64][64]
        float* __restrict__ cwb)                // [64][16][64][64]
{
    const int wh = blockIdx.x;          // w*16 + h
    const int w = wh >> 4, h = wh & 15;
    for (int e = threadIdx.x; e < 4096; e += 256) {
        const int i = e >> 6, j = e & 63;
        const int rel = ((i >> 3) - (j >> 3) + 7) * 15 + (i & 7) - (j & 7) + 7;
        cwb[(size_t)wh * 4096 + e] = bias_table[rel * 16 + h] + mask[(size_t)w * 4096 + e];
    }
}

// ---------------------------------------------------------------------------
// bf16 GEMM, m97 structure (proven ~60 us/instance): 128x128 tile, BK=64,
// 4 waves (2x2), single-buffer 2-barrier loop, global_load_lds 16B with
// pre-swizzled GLOBAL source (slot = blk ^ (row&7), 8 slots per 128B row),
// XCD-aware block swizzle (2048 wgs, 256/XCD).
// C[65536,512] = A_b16 @ W_b16^T + bias, * scale.
// OMODE: 0 = bf16 out [b][h][t][d]; 1 = bf16 out [b][h][d][t]; 2 = fp32 [m][n]
// ---------------------------------------------------------------------------
template<int OMODE>
__global__ __launch_bounds__(256) void gemm_b(
        const u16* __restrict__ A, const u16* __restrict__ Wb,
        const float* __restrict__ bias, float scale, void* __restrict__ outp)
{
    __shared__ __align__(16) u16 As[8192];   // [128][64] swizzled
    __shared__ __align__(16) u16 Bs[8192];

    const int wg = (blockIdx.x & 7) * 256 + (blockIdx.x >> 3);
    const int m0 = (wg >> 2) << 7;
    const int n0 = (wg & 3) << 7;

    const int t = threadIdx.x;
    const int lane = t & 63, wv = t >> 6;
    const int g = lane >> 4, ln = lane & 15;
    const int wr = wv >> 1, wc = wv & 1;
    const int wbase = wv << 6;

    f32x4 acc[4][4];
#pragma unroll
    for (int i = 0; i < 4; i++)
#pragma unroll
        for (int j = 0; j < 4; j++) acc[i][j] = {0.f, 0.f, 0.f, 0.f};

    const u16* Abase = A  + (size_t)m0 * 512;
    const u16* Bbase = Wb + (size_t)n0 * 512;

    for (int k0 = 0; k0 < 512; k0 += 64) {
#pragma unroll
        for (int c = 0; c < 4; c++) {
            const int bi  = (c << 8) + wbase + lane;      // 16B-block 0..1023
            const int row = bi >> 3;
            const int cbs = (bi & 7) ^ (row & 7);
            const size_t go = (size_t)row * 512 + k0 + (cbs << 3);
            load_lds16(Abase + go, &As[((c << 8) + wbase) << 3]);
            load_lds16(Bbase + go, &Bs[((c << 8) + wbase) << 3]);
        }
        __syncthreads();
#pragma unroll
        for (int ks = 0; ks < 2; ks++) {
            bf16x8 af[4], bfr[4];
#pragma unroll
            for (int mt = 0; mt < 4; mt++) {
                const int row = (wr << 6) + (mt << 4) + ln;
                af[mt] = *(const bf16x8*)&As[(row << 6) + ((((ks << 2) + g) ^ (row & 7)) << 3)];
            }
#pragma unroll
            for (int nt = 0; nt < 4; nt++) {
                const int row = (wc << 6) + (nt << 4) + ln;
                bfr[nt] = *(const bf16x8*)&Bs[(row << 6) + ((((ks << 2) + g) ^ (row & 7)) << 3)];
            }
#pragma unroll
            for (int mt = 0; mt < 4; mt++)
#pragma unroll
                for (int nt = 0; nt < 4; nt++)
                    acc[mt][nt] = __builtin_amdgcn_mfma_f32_16x16x32_bf16(
                        af[mt], bfr[nt], acc[mt][nt], 0, 0, 0);
        }
        __syncthreads();
    }

    // ---- epilogue: bias, scale, store ----
#pragma unroll
    for (int mt = 0; mt < 4; mt++) {
#pragma unroll
        for (int nt = 0; nt < 4; nt++) {
            const int n = n0 + (wc << 6) + (nt << 4) + ln;
            const float bv = bias[n];
            const int mbase = m0 + (wr << 6) + (mt << 4) + (g << 2);
            if (OMODE == 0) {
#pragma unroll
                for (int r = 0; r < 4; r++) {
                    const int m = mbase + r;
                    const int b = m >> 6, tt = m & 63, hh = n >> 5, d = n & 31;
                    ((u16*)outp)[((size_t)(b * 16 + hh) * 64 + tt) * 32 + d] =
                        (u16)bfc((acc[mt][nt][r] + bv) * scale);
                }
            } else if (OMODE == 1) {
                short4_t hq;
#pragma unroll
                for (int r = 0; r < 4; r++) hq[r] = bfc((acc[mt][nt][r] + bv) * scale);
                const int b = mbase >> 6, tt = mbase & 63, hh = n >> 5, d = n & 31;
                *(short4_t*)&((u16*)outp)[((size_t)(b * 16 + hh) * 32 + d) * 64 + tt] = hq;
            } else {
#pragma unroll
                for (int r = 0; r < 4; r++) {
                    const int m = mbase + r;
                    ((float*)outp)[(size_t)m * 512 + n] = (acc[mt][nt][r] + bv) * scale;
                }
            }
        }
    }
}

// ---------------------------------------------------------------------------
// Attention: 4 waves/block, one (b,h) per wave.
// S^T = K·Q^T via mfma(K,Q); softmax over j = local reduce + shfl_xor 16/32;
// P -> private per-wave LDS region bf16 [i][j] XOR-swizzled; O^T = V^T·P.
// NO __syncthreads: each wave reads ONLY its own P region (cross-lane but
// same-wave LDS RAW, ordered by compiler lgkmcnt). V fragments hoisted to the
// top so their ~900-cyc HBM latency hides under QK^T + softmax.
// qh,kh: [b][h][t][d] bf16 ; vt: [b][h][d][t] bf16 ; x out: [b][t][h*32+d] bf16
// ---------------------------------------------------------------------------
__global__ __launch_bounds__(256) void attn_kernel(
        const u16* __restrict__ qh, const u16* __restrict__ kh,
        const u16* __restrict__ vt, const float* __restrict__ cwb,
        u16* __restrict__ xout)
{
    __shared__ __align__(16) u16 P[16384];   // 4 waves x 8 KB, wave-private

    const int wv = threadIdx.x >> 6;
    const int bid = (blockIdx.x << 2) + wv;     // b*16 + h
    const int b = bid >> 4, h = bid & 15, w = b & 63;
    const int lane = threadIdx.x & 63, g = lane >> 4, ln = lane & 15;
    const size_t base = (size_t)bid * 2048;
    u16* Pw = &P[wv << 12];

    // ---- hoisted independent loads: V fragments (PV B-operand) ----
    bf16x8 vf[2][2];
#pragma unroll
    for (int ks = 0; ks < 2; ks++)
#pragma unroll
        for (int mt = 0; mt < 2; mt++)
            vf[ks][mt] = *(const bf16x8*)&vt[base + (mt * 16 + ln) * 64 + ks * 32 + g * 8];

    bf16x8 kf[4], qf[4];
#pragma unroll
    for (int mt = 0; mt < 4; mt++)
        kf[mt] = *(const bf16x8*)&kh[base + (mt * 16 + ln) * 32 + g * 8];
#pragma unroll
    for (int nt = 0; nt < 4; nt++)
        qf[nt] = *(const bf16x8*)&qh[base + (nt * 16 + ln) * 32 + g * 8];

    f32x4 acc[4][4];   // acc[mt][nt]: rows j = mt*16+g*4+r, cols i = nt*16+ln
#pragma unroll
    for (int i = 0; i < 4; i++)
#pragma unroll
        for (int j = 0; j < 4; j++) acc[i][j] = {0.f, 0.f, 0.f, 0.f};

#pragma unroll
    for (int mt = 0; mt < 4; mt++)
#pragma unroll
        for (int nt = 0; nt < 4; nt++)
            acc[mt][nt] = __builtin_amdgcn_mfma_f32_16x16x32_bf16(
                kf[mt], qf[nt], acc[mt][nt], 0, 0, 0);

    const float* cw = cwb + (size_t)(w * 16 + h) * 4096;
#pragma unroll
    for (int nt = 0; nt < 4; nt++) {
        const int i = nt * 16 + ln;
#pragma unroll
        for (int mt = 0; mt < 4; mt++) {
            const float4 bm = *(const float4*)&cw[i * 64 + mt * 16 + (g << 2)];
            acc[mt][nt][0] += bm.x; acc[mt][nt][1] += bm.y;
            acc[mt][nt][2] += bm.z; acc[mt][nt][3] += bm.w;
        }
    }

#pragma unroll
    for (int nt = 0; nt < 4; nt++) {
        float mx = acc[0][nt][0];
#pragma unroll
        for (int mt = 0; mt < 4; mt++)
#pragma unroll
            for (int r = 0; r < 4; r++) mx = fmaxf(mx, acc[mt][nt][r]);
        mx = fmaxf(mx, __shfl_xor(mx, 16));
        mx = fmaxf(mx, __shfl_xor(mx, 32));
        float sum = 0.f;
#pragma unroll
        for (int mt = 0; mt < 4; mt++)
#pragma unroll
            for (int r = 0; r < 4; r++) {
                const float p = __expf(acc[mt][nt][r] - mx);
                acc[mt][nt][r] = p;
                sum += p;
            }
        sum += __shfl_xor(sum, 16);
        sum += __shfl_xor(sum, 32);
        const float rs = 1.0f / sum;
        const int i = nt * 16 + ln;
#pragma unroll
        for (int mt = 0; mt < 4; mt++) {
            short4_t hq;
#pragma unroll
            for (int r = 0; r < 4; r++) hq[r] = bfc(acc[mt][nt][r] * rs);
            const int idx = (i * 64 + mt * 16 + (g << 2)) ^ ((i & 7) << 3);
            *(short4_t*)&Pw[idx] = hq;
        }
    }
    // no __syncthreads: P region is wave-private; lgkmcnt orders write->read

    f32x4 oacc[2][4];
#pragma unroll
    for (int i = 0; i < 2; i++)
#pragma unroll
        for (int j = 0; j < 4; j++) oacc[i][j] = {0.f, 0.f, 0.f, 0.f};

#pragma unroll
    for (int ks = 0; ks < 2; ks++) {
        bf16x8 pf[4];
#pragma unroll
        for (int nt = 0; nt < 4; nt++) {
            const int i = nt * 16 + ln;
            pf[nt] = *(const bf16x8*)&Pw[(i * 64 + ks * 32 + g * 8) ^ ((i & 7) << 3)];
        }
#pragma unroll
        for (int mt = 0; mt < 2; mt++)
#pragma unroll
            for (int nt = 0; nt < 4; nt++)
                oacc[mt][nt] = __builtin_amdgcn_mfma_f32_16x16x32_bf16(
                    vf[ks][mt], pf[nt], oacc[mt][nt], 0, 0, 0);
    }

#pragma unroll
    for (int mt = 0; mt < 2; mt++) {
#pragma unroll
        for (int nt = 0; nt < 4; nt++) {
            const int i = nt * 16 + ln, d0 = mt * 16 + (g << 2);
            short4_t hq;
#pragma unroll
            for (int r = 0; r < 4; r++) hq[r] = bfc(oacc[mt][nt][r]);
            *(short4_t*)&xout[((size_t)b * 64 + i) * 512 + h * 32 + d0] = hq;
        }
    }
}

// ---------------------------------------------------------------------------
extern "C" void kernel_launch(void* const* d_in, const int* in_sizes, int n_in,
                              void* d_out, int out_size, void* d_ws, size_t ws_size,
                              hipStream_t stream) {
    const float* q    = (const float*)d_in[0];
    const float* k    = (const float*)d_in[1];
    const float* v    = (const float*)d_in[2];
    const float* mask = (const float*)d_in[3];
    const float* Wq   = (const float*)d_in[4];
    const float* bq   = (const float*)d_in[5];
    const float* Wk   = (const float*)d_in[6];
    const float* bk   = (const float*)d_in[7];
    const float* Wv   = (const float*)d_in[8];
    const float* bv   = (const float*)d_in[9];
    const float* Wp   = (const float*)d_in[10];
    const float* bp   = (const float*)d_in[11];
    const float* bias_table = (const float*)d_in[12];
    float* out = (float*)d_out;

    // ws layout (bytes): t0 (act bf16 / attn out) | qh | kh | vt | cwb | 4x W
    char* ws = (char*)d_ws;
    u16*   t0  = (u16*)(ws);
    u16*   qh  = (u16*)(ws + 67108864);
    u16*   kh  = (u16*)(ws + 134217728);
    u16*   vt  = (u16*)(ws + 201326592);
    float* cwb = (float*)(ws + 268435456);
    u16*   wqb = (u16*)(ws + 285212672);
    u16*   wkb = (u16*)(ws + 285736960);
    u16*   wvb = (u16*)(ws + 286261248);
    u16*   wpb = (u16*)(ws + 286785536);

    const int n8_act = (1024 * 64 * 512) / 8;   // 4,194,304

    cwb_kernel<<<1024, 256, 0, stream>>>(bias_table, mask, cwb);
    wcvt_kernel<<<dim3(128, 4), 256, 0, stream>>>(Wq, Wk, Wv, Wp, wqb, wkb, wvb, wpb);

    cvt_kernel<<<n8_act / 256, 256, 0, stream>>>(q, t0, n8_act);
    gemm_b<0><<<2048, 256, 0, stream>>>(t0, wqb, bq, SCALE_Q, (void*)qh);

    cvt_kernel<<<n8_act / 256, 256, 0, stream>>>(k, t0, n8_act);
    gemm_b<0><<<2048, 256, 0, stream>>>(t0, wkb, bk, 1.0f, (void*)kh);

    cvt_kernel<<<n8_act / 256, 256, 0, stream>>>(v, t0, n8_act);
    gemm_b<1><<<2048, 256, 0, stream>>>(t0, wvb, bv, 1.0f, (void*)vt);

    attn_kernel<<<4096, 256, 0, stream>>>(qh, kh, vt, cwb, t0);

    gemm_b<2><<<2048, 256, 0, stream>>>(t0, wpb, bp, 1.0f, (void*)out);
}